// Round 8
// baseline (2947.348 us; speedup 1.0000x reference)
//
#include <hip/hip_runtime.h>

typedef _Float16 f16;
typedef _Float16 f16x8 __attribute__((ext_vector_type(8)));
typedef _Float16 f16x4 __attribute__((ext_vector_type(4)));
typedef _Float16 f16x2 __attribute__((ext_vector_type(2)));
typedef float f32x4 __attribute__((ext_vector_type(4)));

#define B_ 128
#define T_ 512
#define H_ 192
#define G3 576

// gate prescale constants (folded into weights/biases):
// r,z pre-acts scaled by -log2e  -> sigmoid(u) = rcp(1 + exp2(u~))
// n pre-acts scaled by +2*log2e  -> tanh(v) = 1 - 2*rcp(1 + exp2(v~))
#define SC_RZ (-1.44269504088896f)
#define SC_N  (2.88539008177793f)

// ---- workspace layout (bytes). Total 204,718,080 < 256 MiB. ----
// [0, 150994944)          gxb : gx pre-acts, f16 [d][bblk8(32)][t][w12][lq][l16][s][pair]
// [150994944, 201326592)  hbuf: layer h output, f16 [t][b][384]
//                               (in0 f16 [t][b][128] aliases its first 16.8MB)
// [201326592, 203390976)  wihf: f16 w_ih prescaled (L0 147456, L1 442368, L2 442368)
// [203390976, 204718080)  whhf: f16 w_hh prescaled (3 x 221184)
#define OFF_H   150994944u
#define OFF_WIH 201326592u
#define OFF_WHH 203390976u

__device__ __forceinline__ void gload_lds16(const void* g, void* l) {
  __builtin_amdgcn_global_load_lds(
      (const __attribute__((address_space(1))) unsigned int*)g,
      (__attribute__((address_space(3))) unsigned int*)l, 16, 0, 0);
}

// prescaled gate functions: exactly 2 trans ops, 1 add (+1 fma for tanh)
__device__ __forceinline__ float sigm_pre(float u) {
  return __builtin_amdgcn_rcpf(1.f + __builtin_amdgcn_exp2f(u));
}
__device__ __forceinline__ float tanh_pre(float v) {
  return fmaf(-2.f, __builtin_amdgcn_rcpf(1.f + __builtin_amdgcn_exp2f(v)), 1.f);
}

// ---------------- weight f32 -> f16 conversion with gate prescale ----------------
__global__ void wconv_kernel(const float* __restrict__ w0, const float* __restrict__ h0,
                             const float* __restrict__ w1, const float* __restrict__ h1,
                             const float* __restrict__ w2, const float* __restrict__ h2,
                             f16* __restrict__ wih, f16* __restrict__ whh) {
  const int stride = gridDim.x * blockDim.x;
  for (int i = blockIdx.x * blockDim.x + threadIdx.x; i < 1695744; i += stride) {
    if (i < 1032192) {
      int j, din;
      const float* src;
      if (i < 147456) { j = i; din = 128; src = w0; }
      else if (i < 589824) { j = i - 147456; din = 384; src = w1; }
      else { j = i - 589824; din = 384; src = w2; }
      const int row = j / din;            // 0..1151 = [d][576]
      const int sg = (row % 576) / 192;   // gate type r/z/n
      wih[i] = (f16)(src[j] * (sg == 2 ? SC_N : SC_RZ));
    } else {
      int j = i - 1032192, jl;
      const float* src;
      if (j < 221184) { src = h0; jl = j; }
      else if (j < 442368) { src = h1; jl = j - 221184; }
      else { src = h2; jl = j - 442368; }
      const int row = jl / 192;           // 0..1151
      const int sg = (row % 576) / 192;
      whh[j] = (f16)(src[jl] * (sg == 2 ? SC_N : SC_RZ));
    }
  }
}

// ---------------- embedding gather -> f16, out layout [t][b][128] ----------------
__global__ void embed_kernel(const int* __restrict__ x, const float* __restrict__ emb,
                             f16* __restrict__ o) {
  const int row = (blockIdx.x << 2) + (threadIdx.x >> 6);  // b*512+t
  const int lane = threadIdx.x & 63;
  const int b = row >> 9, t = row & 511;
  const int idx = x[row];
  const float2 v = *(const float2*)(emb + ((size_t)idx << 7) + (lane << 1));
  union { f16 h[2]; unsigned u; } p;
  p.h[0] = (f16)v.x;
  p.h[1] = (f16)v.y;
  *(unsigned*)(o + ((size_t)((t << 7) + b) << 7) + (lane << 1)) = p.u;
}

// ---------------- gx GEMM: gx = X @ w_ih^T + b_ih (f16 MFMA, prescaled) ----------------
template <int DIN>
__global__ __launch_bounds__(256) void gx_gemm(const f16* __restrict__ A,
                                               const f16* __restrict__ W,
                                               const float* __restrict__ bih,
                                               f16* __restrict__ gxo) {
  const int t = blockIdx.x;
  const int nt0 = blockIdx.y << 7;
  const int tid = threadIdx.x;
  const int lane = tid & 63;
  const int w = tid >> 6;
  const int l16 = lane & 15;
  const int lq = lane >> 4;
  const int wm = (w >> 1) << 6;
  const int wn = (w & 1) << 6;

  __shared__ __align__(16) f16 Al[128 * 128];
  __shared__ __align__(16) f16 Bl[128 * 128];

  f32x4 acc[4][4] = {};

  const int srow = tid >> 4;
  const int sc = tid & 15;

  for (int kk = 0; kk < DIN; kk += 128) {
    __syncthreads();
#pragma unroll
    for (int it = 0; it < 8; ++it) {
      const int r = (it << 4) + srow;
      const int cl = sc ^ (r & 7);
      gload_lds16(A + (size_t)(t * B_ + r) * DIN + kk + cl * 8, Al + (it << 11) + tid * 8);
      const int n = nt0 + r;
      gload_lds16(W + (size_t)n * DIN + kk + cl * 8, Bl + (it << 11) + tid * 8);
    }
    __syncthreads();
#pragma unroll
    for (int kt = 0; kt < 4; ++kt) {
      f16x8 af[4], bf[4];
#pragma unroll
      for (int mt = 0; mt < 4; ++mt) {
        const int r = wm + (mt << 4) + l16;
        const int c = ((kt << 2) + lq) ^ (r & 7);
        af[mt] = *(const f16x8*)(Al + (r << 7) + (c << 3));
      }
#pragma unroll
      for (int nt = 0; nt < 4; ++nt) {
        const int r = wn + (nt << 4) + l16;
        const int c = ((kt << 2) + lq) ^ (r & 7);
        bf[nt] = *(const f16x8*)(Bl + (r << 7) + (c << 3));
      }
#pragma unroll
      for (int mt = 0; mt < 4; ++mt)
#pragma unroll
        for (int nt = 0; nt < 4; ++nt)
          acc[mt][nt] = __builtin_amdgcn_mfma_f32_16x16x32_f16(af[mt], bf[nt], acc[mt][nt], 0, 0, 0);
    }
  }
  // epilogue: + scaled b_ih, write scan layout: pairs (rows 2k,2k+1) per lane slot.
  // C frag: row(batch) = lq*4+i, col(gate) = l16.  scan slot lq_s = (lq&1)|((i>>1)<<1).
#pragma unroll
  for (int nt = 0; nt < 4; ++nt) {
    const int ncol = nt0 + wn + (nt << 4);
    const int ntile = ncol >> 4;                 // 0..71
    const int dd = (ntile >= 36) ? 1 : 0;
    const int g = ntile - 36 * dd;
    const int s = g / 12;                        // gate type
    const int c12 = g % 12;                      // scan wave id
    const float bias = bih[ncol + l16] * ((s == 2) ? SC_N : SC_RZ);
#pragma unroll
    for (int mt = 0; mt < 4; ++mt) {
      const int bblk16 = (wm >> 4) + mt;
      const int bblk8 = bblk16 * 2 + (lq >> 1);
      f16x2 p0, p1;
      p0[0] = (f16)(acc[mt][nt][0] + bias);
      p0[1] = (f16)(acc[mt][nt][1] + bias);
      p1[0] = (f16)(acc[mt][nt][2] + bias);
      p1[1] = (f16)(acc[mt][nt][3] + bias);
      const size_t base =
          ((((size_t)(dd * 16 + bblk8) * 512 + t) * 12 + c12) * 4 + (lq & 1)) * 96 +
          l16 * 6 + s * 2;
      *(f16x2*)(gxo + base) = p0;          // rows r0, r0+1 at lq_s = lq&1
      *(f16x2*)(gxo + base + 192) = p1;    // rows at lq_s = (lq&1)+2
    }
  }
}

// ---------------- recurrent scan: two-stream phase pipeline ----------------
// 16 blocks x 768 threads (12 waves, 3/SIMD). Block = (bblk16, d); stream A = batch
// rows b0..b0+7, stream B = b0+8..b0+15 (same dir, shared w_hh). Per iteration:
//   phase1: MFMA_A(k) || gates_B(k-1)   -> barrier
//   phase2: MFMA_B(k) || gates_A(k)     -> barrier
// MFMA and trans/VALU pipes overlap every phase. Duplicate-row A-frags (row=l16&7)
// make acc land dense on all 4 lane-quads: no shuffles, LDS reads broadcast.
__global__ __launch_bounds__(768, 3) void gru_scan(const f16* __restrict__ gx,
                                                   const f16* __restrict__ whh,
                                                   const float* __restrict__ bhh,
                                                   f16* __restrict__ out,
                                                   int last) {
  const int bx = blockIdx.x;
  const int d = bx & 1;
  const int bblk16 = bx >> 1;
  const int bb0 = bblk16 << 4;
  const int tid = threadIdx.x;
  const int lane = tid & 63;
  const int w = tid >> 6;    // 0..11
  const int l16 = lane & 15;
  const int lq = lane >> 4;

  // per-stream 8x192 h tiles, XOR-swizzled; single-buffered (phase barriers suffice)
  __shared__ __align__(16) f16 hT[2][8 * 192];
  for (int i = tid; i < 2 * 8 * 192; i += 768) ((f16*)hT)[i] = (f16)0.f;
  char* cA = (char*)hT[0];
  char* cB = (char*)hT[1];

  int ra[6];
#pragma unroll
  for (int kt = 0; kt < 6; ++kt)
    ra[kt] = (l16 & 7) * 384 + ((kt * 64 + lq * 16) ^ ((l16 & 7) << 4));
  // gate rows owned by this lane: r0, r0+1  (lq0:{0,1} lq1:{4,5} lq2:{2,3} lq3:{6,7})
  const int r0 = ((lq & 1) << 2) | (lq & 2);
  const int cix = (w * 16 + l16) * 2;
  const int wa0 = r0 * 384 + (cix ^ (r0 << 4));
  const int wa1 = (r0 + 1) * 384 + (cix ^ ((r0 + 1) << 4));
  const bool hi = (lq & 2) != 0;  // use acc elems {2,3} (duplicated rows)

  const f16* whd = whh + (size_t)d * (G3 * H_);
  f16x8 wf[3][6];
#pragma unroll
  for (int s = 0; s < 3; ++s) {
    const int nrow = s * 192 + w * 16 + l16;
#pragma unroll
    for (int kt = 0; kt < 6; ++kt)
      wf[s][kt] = *(const f16x8*)(whd + (size_t)nrow * H_ + kt * 32 + lq * 8);
  }
  f32x4 bh4[3];
#pragma unroll
  for (int s = 0; s < 3; ++s) {
    const float bv = bhh[d * G3 + s * 192 + w * 16 + l16] * ((s == 2) ? SC_N : SC_RZ);
    bh4[s] = (f32x4){bv, bv, bv, bv};
  }

  float hrA[2] = {0.f, 0.f}, hrB[2] = {0.f, 0.f};

  const int nsteps = (last && d == 1) ? 1 : T_;
  const bool fwd = (d == 0);
  const long gstep = fwd ? 4608 : -4608;
  const long ostep = fwd ? (long)B_ * 384 : -(long)B_ * 384;
  const int t0 = fwd ? 0 : (T_ - 1);

  const size_t slt = (size_t)((w * 4 + lq) * 16 + l16) * 6;
  const f16* gA = gx + ((size_t)(d * 16 + bblk16 * 2) * 512 + t0) * 4608 + slt;
  const f16* gB = gA + (size_t)512 * 4608;  // bblk8 + 1

  f16* opA = out + ((size_t)t0 * B_ + bb0 + r0) * 384 + d * H_ + w * 16 + l16;
  f16* opB = opA + 8 * 384;

  auto ld3 = [](const f16* p, f16x2 (&g)[3]) {
    g[0] = *(const f16x2*)(p);
    g[1] = *(const f16x2*)(p + 2);
    g[2] = *(const f16x2*)(p + 4);
  };

  f16x2 gA0[3] = {}, gA1[3] = {}, gB0[3] = {}, gB1[3] = {};
  ld3(gA, gA0);
  const f16* gApf = gA + gstep;
  const f16* gBpf = gB;

  f32x4 accB[3];
#pragma unroll
  for (int s = 0; s < 3; ++s) accB[s] = bh4[s];

  __syncthreads();

  auto barrier_ph = [] {
    __builtin_amdgcn_sched_barrier(0);
    asm volatile("s_waitcnt lgkmcnt(0)");
    __builtin_amdgcn_s_barrier();
    __builtin_amdgcn_sched_barrier(0);
  };

  auto gates = [&](const f32x4 (&acc)[3], const f16x2 (&g)[3], float (&hr)[2],
                   char* lds, f16* outp, bool wr) {
    float ae0[3], ae1[3];
#pragma unroll
    for (int s = 0; s < 3; ++s) {
      ae0[s] = hi ? acc[s][2] : acc[s][0];
      ae1[s] = hi ? acc[s][3] : acc[s][1];
    }
    const float rv0 = sigm_pre((float)g[0][0] + ae0[0]);
    const float zv0 = sigm_pre((float)g[1][0] + ae0[1]);
    const float nv0 = tanh_pre((float)g[2][0] + rv0 * ae0[2]);
    const float hv0 = nv0 + zv0 * (hr[0] - nv0);
    const float rv1 = sigm_pre((float)g[0][1] + ae1[0]);
    const float zv1 = sigm_pre((float)g[1][1] + ae1[1]);
    const float nv1 = tanh_pre((float)g[2][1] + rv1 * ae1[2]);
    const float hv1 = nv1 + zv1 * (hr[1] - nv1);
    hr[0] = hv0;
    hr[1] = hv1;
    *(f16*)(lds + wa0) = (f16)hv0;
    *(f16*)(lds + wa1) = (f16)hv1;
    if (wr) {
      outp[0] = (f16)hv0;
      outp[384] = (f16)hv1;
    }
  };

  auto mfma3 = [&](const char* lds, f32x4 (&acc)[3]) {
    {
      const f16x8 af0 = *(const f16x8*)(lds + ra[0]);
#pragma unroll
      for (int s = 0; s < 3; ++s)
        acc[s] = __builtin_amdgcn_mfma_f32_16x16x32_f16(af0, wf[s][0], bh4[s], 0, 0, 0);
    }
#pragma unroll
    for (int kt = 1; kt < 6; ++kt) {
      const f16x8 af = *(const f16x8*)(lds + ra[kt]);
#pragma unroll
      for (int s = 0; s < 3; ++s)
        acc[s] = __builtin_amdgcn_mfma_f32_16x16x32_f16(af, wf[s][kt], acc[s], 0, 0, 0);
    }
  };

  auto iter = [&](int k, f16x2 (&gAc)[3], f16x2 (&gAn)[3], f16x2 (&gBc)[3],
                  f16x2 (&gBn)[3]) {
    // phase 1: prefetch; MFMA_A(k); gates_B(k-1)
    ld3(gBpf, gBn);
    gBpf += gstep;
    if (k + 1 < nsteps) {
      ld3(gApf, gAn);
      gApf += gstep;
    }
    f32x4 accA[3];
    mfma3(cA, accA);
    if (k > 0) {
      gates(accB, gBc, hrB, cB, opB, !last);
      opB += ostep;
    }
    barrier_ph();
    // phase 2: MFMA_B(k); gates_A(k)
    mfma3(cB, accB);
    // A-stream write condition: t == T-1 for the last layer.  t = fwd ? k : T-1-k;
    // for last&&d==1 only k=0 runs (t=T-1)  [round-7 bug: used k==T_-1]
    const bool wrA = (!last) || (k == (fwd ? T_ - 1 : 0));
    gates(accA, gAc, hrA, cA, opA, wrA);
    opA += ostep;
    barrier_ph();
  };

  if (nsteps == 1) {
    iter(0, gA0, gA1, gB0, gB1);
    gates(accB, gB1, hrB, cB, opB, true);   // B step 0 (t = T-1)
  } else {
    for (int k = 0; k < T_; k += 2) {
      iter(k, gA0, gA1, gB0, gB1);
      iter(k + 1, gA1, gA0, gB1, gB0);
    }
    gates(accB, gB0, hrB, cB, opB, true);   // B step T-1
  }
}

// ---------------- FC head ----------------
__global__ void fc_kernel(const f16* __restrict__ h2, const float* __restrict__ w1,
                          const float* __restrict__ b1, const float* __restrict__ w2,
                          const float* __restrict__ b2, float* __restrict__ y) {
  const int b = blockIdx.x;
  const int i = threadIdx.x;
  __shared__ float hs[384];
  __shared__ float us[128];
  const f16* hp = h2 + ((size_t)(T_ - 1) * B_ + b) * 384;
  for (int k = i; k < 384; k += 128) hs[k] = (float)hp[k];
  __syncthreads();
  float a = b1[i];
  for (int k = 0; k < 384; ++k) a = fmaf(w1[i * 384 + k], hs[k], a);
  us[i] = fmaxf(a, 0.f) * w2[i];
  __syncthreads();
  if (i == 0) {
    float s = b2[0];
    for (int k = 0; k < 128; ++k) s += us[k];
    y[b] = s;
  }
}

extern "C" void kernel_launch(void* const* d_in, const int* in_sizes, int n_in,
                              void* d_out, int out_size, void* d_ws, size_t ws_size,
                              hipStream_t stream) {
  const int* x = (const int*)d_in[0];
  const float* emb = (const float*)d_in[1];
  const float* wih[3] = {(const float*)d_in[2], (const float*)d_in[6], (const float*)d_in[10]};
  const float* whh[3] = {(const float*)d_in[3], (const float*)d_in[7], (const float*)d_in[11]};
  const float* bih[3] = {(const float*)d_in[4], (const float*)d_in[8], (const float*)d_in[12]};
  const float* bhh[3] = {(const float*)d_in[5], (const float*)d_in[9], (const float*)d_in[13]};
  const float* fc1w = (const float*)d_in[14];
  const float* fc1b = (const float*)d_in[15];
  const float* fc2w = (const float*)d_in[16];
  const float* fc2b = (const float*)d_in[17];
  float* y = (float*)d_out;

  char* ws = (char*)d_ws;
  f16* gxb = (f16*)(ws);
  f16* hbuf = (f16*)(ws + OFF_H);
  f16* in0 = hbuf;
  f16* wihf = (f16*)(ws + OFF_WIH);
  f16* whhf = (f16*)(ws + OFF_WHH);

  wconv_kernel<<<1024, 256, 0, stream>>>(wih[0], whh[0], wih[1], whh[1], wih[2], whh[2], wihf, whhf);
  embed_kernel<<<16384, 256, 0, stream>>>(x, emb, in0);

  gx_gemm<128><<<dim3(512, 9), 256, 0, stream>>>(in0, wihf, bih[0], gxb);
  gru_scan<<<16, 768, 0, stream>>>(gxb, whhf, bhh[0], hbuf, 0);
  gx_gemm<384><<<dim3(512, 9), 256, 0, stream>>>(hbuf, wihf + 147456, bih[1], gxb);
  gru_scan<<<16, 768, 0, stream>>>(gxb, whhf + 221184, bhh[1], hbuf, 0);
  gx_gemm<384><<<dim3(512, 9), 256, 0, stream>>>(hbuf, wihf + 147456 + 442368, bih[2], gxb);
  gru_scan<<<16, 768, 0, stream>>>(gxb, whhf + 2 * 221184, bhh[2], hbuf, 1);

  fc_kernel<<<128, 128, 0, stream>>>(hbuf, fc1w, fc1b, fc2w, fc2b, y);
}

// Round 9
// 1903.003 us; speedup vs baseline: 1.5488x; 1.5488x over previous
//
#include <hip/hip_runtime.h>

typedef _Float16 f16;
typedef _Float16 f16x8 __attribute__((ext_vector_type(8)));
typedef _Float16 f16x4 __attribute__((ext_vector_type(4)));
typedef _Float16 f16x2 __attribute__((ext_vector_type(2)));
typedef float f32x4 __attribute__((ext_vector_type(4)));

#define B_ 128
#define T_ 512
#define H_ 192
#define G3 576

// gate prescale constants (folded into weights/biases):
// r,z pre-acts scaled by -log2e  -> sigmoid(u) = rcp(1 + exp2(u~))
// n pre-acts scaled by +2*log2e  -> tanh(v) = 1 - 2*rcp(1 + exp2(v~))
#define SC_RZ (-1.44269504088896f)
#define SC_N  (2.88539008177793f)

// ---- workspace layout (bytes). Total 204,718,080 < 256 MiB. ----
// [0, 150994944)          gxb : gx pre-acts, f16 [d][bblk16(8)][t][w12][lq][l16][s*4+i]
// [150994944, 201326592)  hbuf: layer h output, f16 [t][b][384]
//                               (in0 f16 [t][b][128] aliases its first 16.8MB)
// [201326592, 203390976)  wihf: f16 w_ih prescaled (L0 147456, L1 442368, L2 442368)
// [203390976, 204718080)  whhf: f16 w_hh prescaled (3 x 221184)
#define OFF_H   150994944u
#define OFF_WIH 201326592u
#define OFF_WHH 203390976u

__device__ __forceinline__ void gload_lds16(const void* g, void* l) {
  __builtin_amdgcn_global_load_lds(
      (const __attribute__((address_space(1))) unsigned int*)g,
      (__attribute__((address_space(3))) unsigned int*)l, 16, 0, 0);
}

// ---------------- weight f32 -> f16 conversion with gate prescale ----------------
__global__ void wconv_kernel(const float* __restrict__ w0, const float* __restrict__ h0,
                             const float* __restrict__ w1, const float* __restrict__ h1,
                             const float* __restrict__ w2, const float* __restrict__ h2,
                             f16* __restrict__ wih, f16* __restrict__ whh) {
  const int stride = gridDim.x * blockDim.x;
  for (int i = blockIdx.x * blockDim.x + threadIdx.x; i < 1695744; i += stride) {
    if (i < 1032192) {
      int j, din;
      const float* src;
      if (i < 147456) { j = i; din = 128; src = w0; }
      else if (i < 589824) { j = i - 147456; din = 384; src = w1; }
      else { j = i - 589824; din = 384; src = w2; }
      const int row = j / din;            // 0..1151 = [d][576]
      const int sg = (row % 576) / 192;   // gate type r/z/n
      wih[i] = (f16)(src[j] * (sg == 2 ? SC_N : SC_RZ));
    } else {
      int j = i - 1032192, jl;
      const float* src;
      if (j < 221184) { src = h0; jl = j; }
      else if (j < 442368) { src = h1; jl = j - 221184; }
      else { src = h2; jl = j - 442368; }
      const int row = jl / 192;           // 0..1151
      const int sg = (row % 576) / 192;
      whh[j] = (f16)(src[jl] * (sg == 2 ? SC_N : SC_RZ));
    }
  }
}

// ---------------- embedding gather -> f16, out layout [t][b][128] ----------------
__global__ void embed_kernel(const int* __restrict__ x, const float* __restrict__ emb,
                             f16* __restrict__ o) {
  const int row = (blockIdx.x << 2) + (threadIdx.x >> 6);  // b*512+t
  const int lane = threadIdx.x & 63;
  const int b = row >> 9, t = row & 511;
  const int idx = x[row];
  const float2 v = *(const float2*)(emb + ((size_t)idx << 7) + (lane << 1));
  union { f16 h[2]; unsigned u; } p;
  p.h[0] = (f16)v.x;
  p.h[1] = (f16)v.y;
  *(unsigned*)(o + ((size_t)((t << 7) + b) << 7) + (lane << 1)) = p.u;
}

// ---------------- gx GEMM: gx = X @ w_ih^T + b_ih (f16 MFMA, prescaled) ----------------
template <int DIN>
__global__ __launch_bounds__(256) void gx_gemm(const f16* __restrict__ A,
                                               const f16* __restrict__ W,
                                               const float* __restrict__ bih,
                                               f16* __restrict__ gxo) {
  const int t = blockIdx.x;
  const int nt0 = blockIdx.y << 7;
  const int tid = threadIdx.x;
  const int lane = tid & 63;
  const int w = tid >> 6;
  const int l16 = lane & 15;
  const int lq = lane >> 4;
  const int wm = (w >> 1) << 6;
  const int wn = (w & 1) << 6;

  __shared__ __align__(16) f16 Al[128 * 128];
  __shared__ __align__(16) f16 Bl[128 * 128];

  f32x4 acc[4][4] = {};

  const int srow = tid >> 4;
  const int sc = tid & 15;

  for (int kk = 0; kk < DIN; kk += 128) {
    __syncthreads();
#pragma unroll
    for (int it = 0; it < 8; ++it) {
      const int r = (it << 4) + srow;
      const int cl = sc ^ (r & 7);
      gload_lds16(A + (size_t)(t * B_ + r) * DIN + kk + cl * 8, Al + (it << 11) + tid * 8);
      const int n = nt0 + r;
      gload_lds16(W + (size_t)n * DIN + kk + cl * 8, Bl + (it << 11) + tid * 8);
    }
    __syncthreads();
#pragma unroll
    for (int kt = 0; kt < 4; ++kt) {
      f16x8 af[4], bf[4];
#pragma unroll
      for (int mt = 0; mt < 4; ++mt) {
        const int r = wm + (mt << 4) + l16;
        const int c = ((kt << 2) + lq) ^ (r & 7);
        af[mt] = *(const f16x8*)(Al + (r << 7) + (c << 3));
      }
#pragma unroll
      for (int nt = 0; nt < 4; ++nt) {
        const int r = wn + (nt << 4) + l16;
        const int c = ((kt << 2) + lq) ^ (r & 7);
        bf[nt] = *(const f16x8*)(Bl + (r << 7) + (c << 3));
      }
#pragma unroll
      for (int mt = 0; mt < 4; ++mt)
#pragma unroll
        for (int nt = 0; nt < 4; ++nt)
          acc[mt][nt] = __builtin_amdgcn_mfma_f32_16x16x32_f16(af[mt], bf[nt], acc[mt][nt], 0, 0, 0);
    }
  }
  // epilogue: + prescaled b_ih, pack i=0..3 (batch%4) into one 8B store.
  // C frag: row(batch) = lq*4+i, col(gate) = l16.
#pragma unroll
  for (int nt = 0; nt < 4; ++nt) {
    const int ncol = nt0 + wn + (nt << 4);
    const int ntile = ncol >> 4;                 // 0..71
    const int d = (ntile >= 36) ? 1 : 0;
    const int g = ntile - 36 * d;
    const int s = g / 12;                        // gate type
    const int c12 = g % 12;                      // scan wave id
    const float bias = bih[ncol + l16] * ((s == 2) ? SC_N : SC_RZ);
#pragma unroll
    for (int mt = 0; mt < 4; ++mt) {
      const int bblk = (wm >> 4) + mt;
      f16x4 pk;
#pragma unroll
      for (int i = 0; i < 4; ++i) pk[i] = (f16)(acc[mt][nt][i] + bias);
      const size_t off =
          (size_t)(((((d * 8 + bblk) * 512 + t) * 12 + c12) * 4 + lq) * 16 + l16) * 12 + s * 4;
      *(f16x4*)(gxo + off) = pk;
    }
  }
}

// ---------------- recurrent scan (single-phase, engineered) ----------------
// 16 blocks x 768 threads (12 waves, 3/SIMD). Wave w owns gate cols [16w,16w+16)
// for r,z,n. w_hh resident (72 regs). XOR-swizzled LDS h-tile, double-buffered.
// Prescaled gates (no muls), merged rcp for r,z (5 trans/elem). setprio around
// the MFMA cluster. gx prefetched 2 steps ahead; raw barrier (lgkmcnt only).
__global__ __launch_bounds__(768, 3) void gru_scan(const f16* __restrict__ gx,
                                                   const f16* __restrict__ whh,
                                                   const float* __restrict__ bhh,
                                                   f16* __restrict__ out,
                                                   int last) {
  const int bx = blockIdx.x;
  const int d = bx & 1;
  const int bblk = bx >> 1;
  const int b0 = bblk << 4;
  const int tid = threadIdx.x;
  const int lane = tid & 63;
  const int w = tid >> 6;    // 0..11
  const int l16 = lane & 15;
  const int lq = lane >> 4;

  // h tile, XOR-swizzled: elem (row,col) at byte row*384 + ((col*2) ^ ((row&7)<<4))
  __shared__ __align__(16) f16 hl[2 * 16 * 192];   // 12,288 B
  for (int i = tid; i < 2 * 16 * 192; i += 768) hl[i] = (f16)0.f;
  char* cb = (char*)hl;

  // precomputed LDS addresses (buf1 = +6144)
  int ra[6];
#pragma unroll
  for (int kt = 0; kt < 6; ++kt)
    ra[kt] = l16 * 384 + ((kt * 64 + lq * 16) ^ ((l16 & 7) << 4));
  int wa[4];
#pragma unroll
  for (int i = 0; i < 4; ++i) {
    const int row = lq * 4 + i;
    wa[i] = row * 384 + (((w * 16 + l16) * 2) ^ ((row & 7) << 4));
  }

  const f16* whd = whh + (size_t)d * (G3 * H_);
  f16x8 wf[3][6];
#pragma unroll
  for (int s = 0; s < 3; ++s) {
    const int nrow = s * 192 + w * 16 + l16;
#pragma unroll
    for (int kt = 0; kt < 6; ++kt)
      wf[s][kt] = *(const f16x8*)(whd + (size_t)nrow * H_ + kt * 32 + lq * 8);
  }
  f32x4 bh4[3];
#pragma unroll
  for (int s = 0; s < 3; ++s) {
    const float bv = bhh[d * G3 + s * 192 + w * 16 + l16] * ((s == 2) ? SC_N : SC_RZ);
    bh4[s] = (f32x4){bv, bv, bv, bv};
  }

  float hreg[4];
#pragma unroll
  for (int i = 0; i < 4; ++i) hreg[i] = 0.f;

  const int nsteps = (last && d == 1) ? 1 : T_;
  const bool fwd = (d == 0);
  const long gstep = fwd ? 9216 : -9216;          // f16 elems per step
  const long ostep = fwd ? (long)B_ * 384 : -(long)B_ * 384;

  const f16* gbase = gx + (size_t)(d * 8 + bblk) * 4718592 +
                     (size_t)(((w * 4 + lq) * 16 + l16) * 12);
  const int t0 = fwd ? 0 : (T_ - 1);

  // prefetch first two steps' gx
  f16x4 pA[3], pB[3];
  {
    const f16x4* p = (const f16x4*)(gbase + (size_t)t0 * 9216);
#pragma unroll
    for (int j = 0; j < 3; ++j) pA[j] = p[j];
  }
  if (nsteps > 1) {
    const f16x4* p = (const f16x4*)(gbase + (size_t)t0 * 9216 + gstep);
#pragma unroll
    for (int j = 0; j < 3; ++j) pB[j] = p[j];
  }
  const f16* gptr = gbase + (size_t)t0 * 9216 + 2 * gstep;  // 2 steps ahead
  f16* outp = out + ((size_t)t0 * B_ + b0 + (lq << 2)) * 384 + d * H_ + w * 16 + l16;

  __syncthreads();

  // one GRU step: consumes pc (this step's gx), reloads pc 2 steps ahead
  auto body = [&](int step, int buf, f16x4 (&pc)[3]) {
    const int bo = buf ? 6144 : 0;
    // gh = h @ w_hh^T with prescaled b_hh as C-init of the first MFMA
    f32x4 acc[3];
    __builtin_amdgcn_s_setprio(1);
    {
      const f16x8 af0 = *(const f16x8*)(cb + ra[0] + bo);
#pragma unroll
      for (int s = 0; s < 3; ++s)
        acc[s] = __builtin_amdgcn_mfma_f32_16x16x32_f16(af0, wf[s][0], bh4[s], 0, 0, 0);
    }
#pragma unroll
    for (int kt = 1; kt < 6; ++kt) {
      const f16x8 af = *(const f16x8*)(cb + ra[kt] + bo);
#pragma unroll
      for (int s = 0; s < 3; ++s)
        acc[s] = __builtin_amdgcn_mfma_f32_16x16x32_f16(af, wf[s][kt], acc[s], 0, 0, 0);
    }
    __builtin_amdgcn_s_setprio(0);
    // snapshot current gx, issue reload 2 steps ahead
    const f16x4 g0 = pc[0], g1 = pc[1], g2 = pc[2];
    if (step + 2 < nsteps) {
      const f16x4* p = (const f16x4*)gptr;
#pragma unroll
      for (int j = 0; j < 3; ++j) pc[j] = p[j];
      gptr += gstep;
    }
    const int t = fwd ? step : (T_ - 1 - step);
    const bool wr = (!last) || (t == T_ - 1);
    const int bo2 = buf ? 0 : 6144;   // write to other buffer
#pragma unroll
    for (int i = 0; i < 4; ++i) {
      // prescaled gates; merged reciprocal for the two sigmoids
      const float ur = (float)g0[i] + acc[0][i];
      const float uz = (float)g1[i] + acc[1][i];
      const float Er = __builtin_amdgcn_exp2f(ur);
      const float Ez = __builtin_amdgcn_exp2f(uz);
      const float dr = 1.f + Er, dz = 1.f + Ez;
      const float Rp = __builtin_amdgcn_rcpf(dr * dz);
      const float rv = dz * Rp;            // sigmoid(r~)
      const float zv = dr * Rp;            // sigmoid(z~)
      const float vn = fmaf(rv, acc[2][i], (float)g2[i]);
      const float Rn = __builtin_amdgcn_rcpf(1.f + __builtin_amdgcn_exp2f(vn));
      const float nv = fmaf(-2.f, Rn, 1.f);  // tanh
      const float hv = nv + zv * (hreg[i] - nv);
      hreg[i] = hv;
      *(f16*)(cb + wa[i] + bo2) = (f16)hv;
      if (wr) outp[i * 384] = (f16)hv;
    }
    outp += ostep;
    // order LDS; keep global loads/stores in flight across the barrier
    __builtin_amdgcn_sched_barrier(0);
    asm volatile("s_waitcnt lgkmcnt(0)");
    __builtin_amdgcn_s_barrier();
    __builtin_amdgcn_sched_barrier(0);
  };

  if (nsteps == 1) {
    body(0, 0, pA);
  } else {
    for (int step = 0; step < T_; step += 2) {
      body(step, 0, pA);
      body(step + 1, 1, pB);
    }
  }
}

// ---------------- FC head ----------------
__global__ void fc_kernel(const f16* __restrict__ h2, const float* __restrict__ w1,
                          const float* __restrict__ b1, const float* __restrict__ w2,
                          const float* __restrict__ b2, float* __restrict__ y) {
  const int b = blockIdx.x;
  const int i = threadIdx.x;
  __shared__ float hs[384];
  __shared__ float us[128];
  const f16* hp = h2 + ((size_t)(T_ - 1) * B_ + b) * 384;
  for (int k = i; k < 384; k += 128) hs[k] = (float)hp[k];
  __syncthreads();
  float a = b1[i];
  for (int k = 0; k < 384; ++k) a = fmaf(w1[i * 384 + k], hs[k], a);
  us[i] = fmaxf(a, 0.f) * w2[i];
  __syncthreads();
  if (i == 0) {
    float s = b2[0];
    for (int k = 0; k < 128; ++k) s += us[k];
    y[b] = s;
  }
}

extern "C" void kernel_launch(void* const* d_in, const int* in_sizes, int n_in,
                              void* d_out, int out_size, void* d_ws, size_t ws_size,
                              hipStream_t stream) {
  const int* x = (const int*)d_in[0];
  const float* emb = (const float*)d_in[1];
  const float* wih[3] = {(const float*)d_in[2], (const float*)d_in[6], (const float*)d_in[10]};
  const float* whh[3] = {(const float*)d_in[3], (const float*)d_in[7], (const float*)d_in[11]};
  const float* bih[3] = {(const float*)d_in[4], (const float*)d_in[8], (const float*)d_in[12]};
  const float* bhh[3] = {(const float*)d_in[5], (const float*)d_in[9], (const float*)d_in[13]};
  const float* fc1w = (const float*)d_in[14];
  const float* fc1b = (const float*)d_in[15];
  const float* fc2w = (const float*)d_in[16];
  const float* fc2b = (const float*)d_in[17];
  float* y = (float*)d_out;

  char* ws = (char*)d_ws;
  f16* gxb = (f16*)(ws);
  f16* hbuf = (f16*)(ws + OFF_H);
  f16* in0 = hbuf;
  f16* wihf = (f16*)(ws + OFF_WIH);
  f16* whhf = (f16*)(ws + OFF_WHH);

  wconv_kernel<<<1024, 256, 0, stream>>>(wih[0], whh[0], wih[1], whh[1], wih[2], whh[2], wihf, whhf);
  embed_kernel<<<16384, 256, 0, stream>>>(x, emb, in0);

  gx_gemm<128><<<dim3(512, 9), 256, 0, stream>>>(in0, wihf, bih[0], gxb);
  gru_scan<<<16, 768, 0, stream>>>(gxb, whhf, bhh[0], hbuf, 0);
  gx_gemm<384><<<dim3(512, 9), 256, 0, stream>>>(hbuf, wihf + 147456, bih[1], gxb);
  gru_scan<<<16, 768, 0, stream>>>(gxb, whhf + 221184, bhh[1], hbuf, 0);
  gx_gemm<384><<<dim3(512, 9), 256, 0, stream>>>(hbuf, wihf + 147456 + 442368, bih[2], gxb);
  gru_scan<<<16, 768, 0, stream>>>(gxb, whhf + 2 * 221184, bhh[2], hbuf, 1);

  fc_kernel<<<128, 128, 0, stream>>>(hbuf, fc1w, fc1b, fc2w, fc2b, y);
}

// Round 11
// 1543.739 us; speedup vs baseline: 1.9092x; 1.2327x over previous
//
#include <hip/hip_runtime.h>

typedef _Float16 f16;
typedef _Float16 f16x8 __attribute__((ext_vector_type(8)));
typedef _Float16 f16x4 __attribute__((ext_vector_type(4)));
typedef _Float16 f16x2 __attribute__((ext_vector_type(2)));
typedef float f32x4 __attribute__((ext_vector_type(4)));

#define B_ 128
#define T_ 512
#define H_ 192
#define G3 576

// gate prescale constants (folded into weights/biases):
// r,z pre-acts scaled by -log2e  -> sigmoid(u) = rcp(1 + exp2(u~))
// n pre-acts scaled by +2*log2e  -> tanh(v) = 1 - 2*rcp(1 + exp2(v~))
#define SC_RZ (-1.44269504088896f)
#define SC_N  (2.88539008177793f)

// ---- workspace layout (bytes). Total 204,718,080 < 256 MiB. ----
// [0, 150994944)          gxb : gx pre-acts, f16 [d][bblk8(32)][t][w12][lq][l16][s][pair]
//                               per (d,bblk8): 512*4608 f16; per t: 4608 f16
// [150994944, 201326592)  hbuf: layer h output, f16 [t][b][384]
//                               (in0 f16 [t][b][128] aliases its first 16.8MB)
// [201326592, 203390976)  wihf: f16 w_ih prescaled (L0 147456, L1 442368, L2 442368)
// [203390976, 204718080)  whhf: f16 w_hh prescaled (3 x 221184)
#define OFF_H   150994944u
#define OFF_WIH 201326592u
#define OFF_WHH 203390976u

__device__ __forceinline__ void gload_lds16(const void* g, void* l) {
  __builtin_amdgcn_global_load_lds(
      (const __attribute__((address_space(1))) unsigned int*)g,
      (__attribute__((address_space(3))) unsigned int*)l, 16, 0, 0);
}

// ---------------- weight f32 -> f16 conversion with gate prescale ----------------
__global__ void wconv_kernel(const float* __restrict__ w0, const float* __restrict__ h0,
                             const float* __restrict__ w1, const float* __restrict__ h1,
                             const float* __restrict__ w2, const float* __restrict__ h2,
                             f16* __restrict__ wih, f16* __restrict__ whh) {
  const int stride = gridDim.x * blockDim.x;
  for (int i = blockIdx.x * blockDim.x + threadIdx.x; i < 1695744; i += stride) {
    if (i < 1032192) {
      int j, din;
      const float* src;
      if (i < 147456) { j = i; din = 128; src = w0; }
      else if (i < 589824) { j = i - 147456; din = 384; src = w1; }
      else { j = i - 589824; din = 384; src = w2; }
      const int row = j / din;            // 0..1151 = [d][576]
      const int sg = (row % 576) / 192;   // gate type r/z/n
      wih[i] = (f16)(src[j] * (sg == 2 ? SC_N : SC_RZ));
    } else {
      int j = i - 1032192, jl;
      const float* src;
      if (j < 221184) { src = h0; jl = j; }
      else if (j < 442368) { src = h1; jl = j - 221184; }
      else { src = h2; jl = j - 442368; }
      const int row = jl / 192;           // 0..1151
      const int sg = (row % 576) / 192;
      whh[j] = (f16)(src[jl] * (sg == 2 ? SC_N : SC_RZ));
    }
  }
}

// ---------------- embedding gather -> f16, out layout [t][b][128] ----------------
__global__ void embed_kernel(const int* __restrict__ x, const float* __restrict__ emb,
                             f16* __restrict__ o) {
  const int row = (blockIdx.x << 2) + (threadIdx.x >> 6);  // b*512+t
  const int lane = threadIdx.x & 63;
  const int b = row >> 9, t = row & 511;
  const int idx = x[row];
  const float2 v = *(const float2*)(emb + ((size_t)idx << 7) + (lane << 1));
  union { f16 h[2]; unsigned u; } p;
  p.h[0] = (f16)v.x;
  p.h[1] = (f16)v.y;
  *(unsigned*)(o + ((size_t)((t << 7) + b) << 7) + (lane << 1)) = p.u;
}

// ---------------- gx GEMM: gx = X @ w_ih^T + b_ih (f16 MFMA, prescaled) ----------------
template <int DIN>
__global__ __launch_bounds__(256) void gx_gemm(const f16* __restrict__ A,
                                               const f16* __restrict__ W,
                                               const float* __restrict__ bih,
                                               f16* __restrict__ gxo) {
  const int t = blockIdx.x;
  const int nt0 = blockIdx.y << 7;
  const int tid = threadIdx.x;
  const int lane = tid & 63;
  const int w = tid >> 6;
  const int l16 = lane & 15;
  const int lq = lane >> 4;
  const int wm = (w >> 1) << 6;
  const int wn = (w & 1) << 6;

  __shared__ __align__(16) f16 Al[128 * 128];
  __shared__ __align__(16) f16 Bl[128 * 128];

  f32x4 acc[4][4] = {};

  const int srow = tid >> 4;
  const int sc = tid & 15;

  for (int kk = 0; kk < DIN; kk += 128) {
    __syncthreads();
#pragma unroll
    for (int it = 0; it < 8; ++it) {
      const int r = (it << 4) + srow;
      const int cl = sc ^ (r & 7);
      gload_lds16(A + (size_t)(t * B_ + r) * DIN + kk + cl * 8, Al + (it << 11) + tid * 8);
      const int n = nt0 + r;
      gload_lds16(W + (size_t)n * DIN + kk + cl * 8, Bl + (it << 11) + tid * 8);
    }
    __syncthreads();
#pragma unroll
    for (int kt = 0; kt < 4; ++kt) {
      f16x8 af[4], bf[4];
#pragma unroll
      for (int mt = 0; mt < 4; ++mt) {
        const int r = wm + (mt << 4) + l16;
        const int c = ((kt << 2) + lq) ^ (r & 7);
        af[mt] = *(const f16x8*)(Al + (r << 7) + (c << 3));
      }
#pragma unroll
      for (int nt = 0; nt < 4; ++nt) {
        const int r = wn + (nt << 4) + l16;
        const int c = ((kt << 2) + lq) ^ (r & 7);
        bf[nt] = *(const f16x8*)(Bl + (r << 7) + (c << 3));
      }
#pragma unroll
      for (int mt = 0; mt < 4; ++mt)
#pragma unroll
        for (int nt = 0; nt < 4; ++nt)
          acc[mt][nt] = __builtin_amdgcn_mfma_f32_16x16x32_f16(af[mt], bf[nt], acc[mt][nt], 0, 0, 0);
    }
  }
  // epilogue: + prescaled b_ih; pair layout (verified rounds 8/10 first-call).
  // C frag: row(batch) = lq*4+i, col(gate) = l16.  store slot lq_s = (lq&1) | ((i>>1)<<1).
#pragma unroll
  for (int nt = 0; nt < 4; ++nt) {
    const int ncol = nt0 + wn + (nt << 4);
    const int ntile = ncol >> 4;                 // 0..71
    const int dd = (ntile >= 36) ? 1 : 0;
    const int g = ntile - 36 * dd;
    const int s = g / 12;                        // gate type
    const int c12 = g % 12;                      // scan wave id
    const float bias = bih[ncol + l16] * ((s == 2) ? SC_N : SC_RZ);
#pragma unroll
    for (int mt = 0; mt < 4; ++mt) {
      const int bblk16 = (wm >> 4) + mt;
      const int bblk8 = bblk16 * 2 + (lq >> 1);
      f16x2 p0, p1;
      p0[0] = (f16)(acc[mt][nt][0] + bias);
      p0[1] = (f16)(acc[mt][nt][1] + bias);
      p1[0] = (f16)(acc[mt][nt][2] + bias);
      p1[1] = (f16)(acc[mt][nt][3] + bias);
      const size_t base =
          ((((size_t)(dd * 16 + bblk8) * 512 + t) * 12 + c12) * 4 + (lq & 1)) * 96 +
          l16 * 6 + s * 2;
      *(f16x2*)(gxo + base) = p0;          // rows (lq&1)*4 + {0,1} of the 8-row block
      *(f16x2*)(gxo + base + 192) = p1;    // rows (lq&1)*4 + {2,3}
    }
  }
}

// ---------------- recurrent scan: 8 rows/block, 32 blocks ----------------
// 32 blocks x 768 threads (12 waves, 3/SIMD). Block = (bblk8, d), batch rows
// b0..b0+7. Wave w owns gate cols [16w,16w+16) for r,z,n: 18 MFMA/wave/step.
// Duplicate-row A-frags (row=l16&7) spread 8 rows over all 4 lane-quads: 2 gate
// elems/lane, no shuffles. Prescaled gates, merged rcp for r,z. gx prefetch
// issued at TOP of body (hides under MFMA phase). Plain __syncthreads() per
// step: architecturally-defined full drain (round-10 raw-barrier variant
// diverged under graph replay).
__global__ __launch_bounds__(768, 3) void gru_scan(const f16* __restrict__ gx,
                                                   const f16* __restrict__ whh,
                                                   const float* __restrict__ bhh,
                                                   f16* __restrict__ out,
                                                   int last) {
  const int bx = blockIdx.x;
  const int d = bx & 1;
  const int bblk8 = bx >> 1;   // 0..15
  const int b0 = bblk8 << 3;
  const int tid = threadIdx.x;
  const int lane = tid & 63;
  const int w = tid >> 6;      // 0..11
  const int l16 = lane & 15;
  const int lq = lane >> 4;

  // h tile 8x192, XOR-swizzled, double-buffered (3072 B per buffer)
  __shared__ __align__(16) f16 hl[2 * 8 * 192];
  for (int i = tid; i < 2 * 8 * 192; i += 768) hl[i] = (f16)0.f;
  char* cb = (char*)hl;

  int ra[6];
#pragma unroll
  for (int kt = 0; kt < 6; ++kt)
    ra[kt] = (l16 & 7) * 384 + ((kt * 64 + lq * 16) ^ ((l16 & 7) << 4));
  // rows owned by this lane: r0, r0+1  (lq0:{0,1} lq1:{4,5} lq2:{2,3} lq3:{6,7})
  const int r0 = ((lq & 1) << 2) | (lq & 2);
  const int cix = (w * 16 + l16) * 2;
  const int wa0 = r0 * 384 + (cix ^ (r0 << 4));
  const int wa1 = (r0 + 1) * 384 + (cix ^ ((r0 + 1) << 4));
  const bool hi = (lq & 2) != 0;  // use acc elems {2,3} (duplicated rows)

  const f16* whd = whh + (size_t)d * (G3 * H_);
  f16x8 wf[3][6];
#pragma unroll
  for (int s = 0; s < 3; ++s) {
    const int nrow = s * 192 + w * 16 + l16;
#pragma unroll
    for (int kt = 0; kt < 6; ++kt)
      wf[s][kt] = *(const f16x8*)(whd + (size_t)nrow * H_ + kt * 32 + lq * 8);
  }
  f32x4 bh4[3];
#pragma unroll
  for (int s = 0; s < 3; ++s) {
    const float bv = bhh[d * G3 + s * 192 + w * 16 + l16] * ((s == 2) ? SC_N : SC_RZ);
    bh4[s] = (f32x4){bv, bv, bv, bv};
  }

  float hr0 = 0.f, hr1 = 0.f;

  const int nsteps = (last && d == 1) ? 1 : T_;
  const bool fwd = (d == 0);
  const long gstep = fwd ? 4608 : -4608;          // f16 elems per step
  const long ostep = fwd ? (long)B_ * 384 : -(long)B_ * 384;
  const int t0 = fwd ? 0 : (T_ - 1);

  // per-lane gx slot: 6 f16 = [s][pair], 12B
  const f16* gbase = gx + (size_t)(d * 16 + bblk8) * 2359296 +
                     (size_t)(((w * 4 + lq) * 16 + l16) * 6);

  auto ld3 = [](const f16* p, f16x2 (&g)[3]) {
    g[0] = *(const f16x2*)(p);
    g[1] = *(const f16x2*)(p + 2);
    g[2] = *(const f16x2*)(p + 4);
  };

  f16x2 pA[3] = {}, pB[3] = {};
  ld3(gbase + (size_t)t0 * 4608, pA);
  if (nsteps > 1) ld3(gbase + (size_t)t0 * 4608 + gstep, pB);
  const f16* gptr = gbase + (size_t)t0 * 4608 + 2 * gstep;  // 2 steps ahead
  f16* outp = out + ((size_t)t0 * B_ + b0 + r0) * 384 + d * H_ + w * 16 + l16;

  __syncthreads();

  auto body = [&](int step, int buf, f16x2 (&pc)[3]) {
    const int bo = buf ? 3072 : 0;
    // snapshot this step's gx; issue reload for step+2 EARLY so HBM latency
    // hides under the MFMA phase + gates before the end-of-step drain
    const f16x2 g0 = pc[0], g1 = pc[1], g2 = pc[2];
    if (step + 2 < nsteps) {
      ld3(gptr, pc);
      gptr += gstep;
    }
    f32x4 acc[3];
    {
      const f16x8 af0 = *(const f16x8*)(cb + ra[0] + bo);
#pragma unroll
      for (int s = 0; s < 3; ++s)
        acc[s] = __builtin_amdgcn_mfma_f32_16x16x32_f16(af0, wf[s][0], bh4[s], 0, 0, 0);
    }
#pragma unroll
    for (int kt = 1; kt < 6; ++kt) {
      const f16x8 af = *(const f16x8*)(cb + ra[kt] + bo);
#pragma unroll
      for (int s = 0; s < 3; ++s)
        acc[s] = __builtin_amdgcn_mfma_f32_16x16x32_f16(af, wf[s][kt], acc[s], 0, 0, 0);
    }
    const int t = fwd ? step : (T_ - 1 - step);
    const bool wr = (!last) || (t == T_ - 1);
    const int bo2 = buf ? 0 : 3072;   // write to other buffer
    // this lane's two gate elements
    const float a0r = hi ? acc[0][2] : acc[0][0];
    const float a0z = hi ? acc[1][2] : acc[1][0];
    const float a0n = hi ? acc[2][2] : acc[2][0];
    const float a1r = hi ? acc[0][3] : acc[0][1];
    const float a1z = hi ? acc[1][3] : acc[1][1];
    const float a1n = hi ? acc[2][3] : acc[2][1];
    {
      const float ur = (float)g0[0] + a0r;
      const float uz = (float)g1[0] + a0z;
      const float dr = 1.f + __builtin_amdgcn_exp2f(ur);
      const float dz = 1.f + __builtin_amdgcn_exp2f(uz);
      const float Rp = __builtin_amdgcn_rcpf(dr * dz);
      const float rv = dz * Rp, zv = dr * Rp;
      const float vn = fmaf(rv, a0n, (float)g2[0]);
      const float nv = fmaf(-2.f, __builtin_amdgcn_rcpf(1.f + __builtin_amdgcn_exp2f(vn)), 1.f);
      const float hv = nv + zv * (hr0 - nv);
      hr0 = hv;
      *(f16*)(cb + wa0 + bo2) = (f16)hv;
      if (wr) outp[0] = (f16)hv;
    }
    {
      const float ur = (float)g0[1] + a1r;
      const float uz = (float)g1[1] + a1z;
      const float dr = 1.f + __builtin_amdgcn_exp2f(ur);
      const float dz = 1.f + __builtin_amdgcn_exp2f(uz);
      const float Rp = __builtin_amdgcn_rcpf(dr * dz);
      const float rv = dz * Rp, zv = dr * Rp;
      const float vn = fmaf(rv, a1n, (float)g2[1]);
      const float nv = fmaf(-2.f, __builtin_amdgcn_rcpf(1.f + __builtin_amdgcn_exp2f(vn)), 1.f);
      const float hv = nv + zv * (hr1 - nv);
      hr1 = hv;
      *(f16*)(cb + wa1 + bo2) = (f16)hv;
      if (wr) outp[384] = (f16)hv;
    }
    outp += ostep;
    __syncthreads();
  };

  if (nsteps == 1) {
    body(0, 0, pA);
  } else {
    for (int step = 0; step < T_; step += 2) {
      body(step, 0, pA);
      body(step + 1, 1, pB);
    }
  }
}

// ---------------- FC head ----------------
__global__ void fc_kernel(const f16* __restrict__ h2, const float* __restrict__ w1,
                          const float* __restrict__ b1, const float* __restrict__ w2,
                          const float* __restrict__ b2, float* __restrict__ y) {
  const int b = blockIdx.x;
  const int i = threadIdx.x;
  __shared__ float hs[384];
  __shared__ float us[128];
  const f16* hp = h2 + ((size_t)(T_ - 1) * B_ + b) * 384;
  for (int k = i; k < 384; k += 128) hs[k] = (float)hp[k];
  __syncthreads();
  float a = b1[i];
  for (int k = 0; k < 384; ++k) a = fmaf(w1[i * 384 + k], hs[k], a);
  us[i] = fmaxf(a, 0.f) * w2[i];
  __syncthreads();
  if (i == 0) {
    float s = b2[0];
    for (int k = 0; k < 128; ++k) s += us[k];
    y[b] = s;
  }
}

extern "C" void kernel_launch(void* const* d_in, const int* in_sizes, int n_in,
                              void* d_out, int out_size, void* d_ws, size_t ws_size,
                              hipStream_t stream) {
  const int* x = (const int*)d_in[0];
  const float* emb = (const float*)d_in[1];
  const float* wih[3] = {(const float*)d_in[2], (const float*)d_in[6], (const float*)d_in[10]};
  const float* whh[3] = {(const float*)d_in[3], (const float*)d_in[7], (const float*)d_in[11]};
  const float* bih[3] = {(const float*)d_in[4], (const float*)d_in[8], (const float*)d_in[12]};
  const float* bhh[3] = {(const float*)d_in[5], (const float*)d_in[9], (const float*)d_in[13]};
  const float* fc1w = (const float*)d_in[14];
  const float* fc1b = (const float*)d_in[15];
  const float* fc2w = (const float*)d_in[16];
  const float* fc2b = (const float*)d_in[17];
  float* y = (float*)d_out;

  char* ws = (char*)d_ws;
  f16* gxb = (f16*)(ws);
  f16* hbuf = (f16*)(ws + OFF_H);
  f16* in0 = hbuf;
  f16* wihf = (f16*)(ws + OFF_WIH);
  f16* whhf = (f16*)(ws + OFF_WHH);

  wconv_kernel<<<1024, 256, 0, stream>>>(wih[0], whh[0], wih[1], whh[1], wih[2], whh[2], wihf, whhf);
  embed_kernel<<<16384, 256, 0, stream>>>(x, emb, in0);

  gx_gemm<128><<<dim3(512, 9), 256, 0, stream>>>(in0, wihf, bih[0], gxb);
  gru_scan<<<32, 768, 0, stream>>>(gxb, whhf, bhh[0], hbuf, 0);
  gx_gemm<384><<<dim3(512, 9), 256, 0, stream>>>(hbuf, wihf + 147456, bih[1], gxb);
  gru_scan<<<32, 768, 0, stream>>>(gxb, whhf + 221184, bhh[1], hbuf, 0);
  gx_gemm<384><<<dim3(512, 9), 256, 0, stream>>>(hbuf, wihf + 147456 + 442368, bih[2], gxb);
  gru_scan<<<32, 768, 0, stream>>>(gxb, whhf + 2 * 221184, bhh[2], hbuf, 1);

  fc_kernel<<<128, 128, 0, stream>>>(hbuf, fc1w, fc1b, fc2w, fc2b, y);
}